// Round 10
// baseline (128.789 us; speedup 1.0000x reference)
//
#include <hip/hip_runtime.h>

#define BINS 10
#define TPB  256
#define NB_MAX 2048
#define FTPB 1024   // finalize block size
#define KPACK 4096.0f

// Pass 1: per-bin (count,sum) fused into ONE value per element:
//   v = valid ? (bce + 4096) : 0, accumulated into hist[bin][tid] via
//   ds_add_f32 (fire-and-forget LDS atomic -- no return, no lgkm wait, no
//   VALU RMW chain). Per-thread column => never same-address; LDS bank is
//   tid%32 for every bin => 2 lanes/bank (free). Replaces R7-R9's 30-instr
//   one-hot select chain (and the 80-shfl epilogue) after three flat rounds
//   showed the wave's dynamic instruction mass, not memory, is the limiter.
// Per-cell fused value <= 20*(4096+10) ~ 82K: count=floor(x/4096) exact,
// bce part carries <0.1 rounding per cell -> ~1e-5 relative on final loss.
__global__ __launch_bounds__(TPB, 4) void ghmc_hist_kernel(
    const float4* __restrict__ pred4,
    const int4*   __restrict__ tgt4,
    const int4*   __restrict__ lw4,
    float* __restrict__ part,      // [nb][2*BINS]
    int n4, int n)
{
    __shared__ float hist[BINS][TPB];   // 10 KB, per-thread columns
    __shared__ float tbl[2 * BINS];     // block-level separated results

    const int tid = threadIdx.x;
#pragma unroll
    for (int b = 0; b < BINS; ++b) hist[b][tid] = 0.f;   // own column only
    if (tid < 2 * BINS) tbl[tid] = 0.f;                  // used after barrier

    auto proc = [&](float p, int t, int w) {
        // q = t ? -p : p  ==>  sigmoid(q) = g,  softplus(q) = bce
        float q     = __int_as_float(__float_as_int(p) ^ (t << 31));
        float e     = __expf(-fabsf(q));          // v_mul + v_exp
        float d     = 1.f + e;
        float r     = __builtin_amdgcn_rcpf(d);
        float num   = (q >= 0.f) ? 1.0f : e;      // sigmoid numerator
        float sig10 = num * (10.f * r);           // 10*sigmoid(q) in [0,10]
        int bin     = (int)sig10;
        bin = bin < (BINS - 1) ? bin : (BINS - 1);
        float bce   = fmaxf(q, 0.f) + __logf(d);  // softplus(q)
        float v     = (w > 0) ? (bce + KPACK) : 0.f;
        atomicAdd(&hist[bin][tid], v);            // ds_add_f32, no return
    };

    const int tid_   = tid;
    const int stride = gridDim.x * TPB;
    const int base   = blockIdx.x * TPB + tid_;
    const int full   = n4 / stride;   // uniform trip count (5 at bench shape)

    int i = base;
    float4 pA; int4 tA, wA;
    if (full > 0) { pA = pred4[i]; tA = tgt4[i]; wA = lw4[i]; }
    for (int k = 0; k < full - 1; ++k) {
        const int j = i + stride;
        float4 pB = pred4[j]; int4 tB = tgt4[j]; int4 wB = lw4[j];
        proc(pA.x, tA.x, wA.x); proc(pA.y, tA.y, wA.y);
        proc(pA.z, tA.z, wA.z); proc(pA.w, tA.w, wA.w);
        pA = pB; tA = tB; wA = wB;
        i = j;
    }
    if (full > 0) {
        proc(pA.x, tA.x, wA.x); proc(pA.y, tA.y, wA.y);
        proc(pA.z, tA.z, wA.z); proc(pA.w, tA.w, wA.w);
    }
    // remainder quad (cold at bench shape)
    {
        const int j = base + full * stride;
        if (j < n4) {
            float4 p = pred4[j]; int4 t = tgt4[j]; int4 w = lw4[j];
            proc(p.x, t.x, w.x); proc(p.y, t.y, w.y);
            proc(p.z, t.z, w.z); proc(p.w, t.w, w.w);
        }
    }
    // scalar tail (cold at bench shape)
    if (blockIdx.x == 0 && tid_ < (n & 3)) {
        const float* predf = (const float*)pred4;
        const int*   tgtf  = (const int*)tgt4;
        const int*   lwf   = (const int*)lw4;
        const int j = n4 * 4 + tid_;
        proc(predf[j], tgtf[j], lwf[j]);
    }

    __syncthreads();   // drains lgkm: all ds_adds visible

    // Each thread separates its OWN column (exact), accumulates into tbl.
    {
        float s_sum = 0.f, s_cnt_dummy;
        (void)s_cnt_dummy;
#pragma unroll
        for (int b = 0; b < BINS; ++b) {
            float x  = hist[b][tid_];
            float Cf = floorf(x * (1.f / KPACK));
            float Sf = x - KPACK * Cf;
            atomicAdd(&tbl[b], Sf);           // ds_add_f32
            atomicAdd(&tbl[BINS + b], Cf);    // ds_add_f32
        }
        (void)s_sum;
    }
    __syncthreads();

    if (tid_ < 2 * BINS)
        part[blockIdx.x * (2 * BINS) + tid_] = tbl[tid_];   // contiguous record
}

// Pass 2: reduce nb 20-float records with full ILP, compute the scalar loss.
__global__ __launch_bounds__(FTPB) void ghmc_final_kernel(
    const float* __restrict__ part, float* __restrict__ out, int nb)
{
    float acc[2 * BINS];
#pragma unroll
    for (int v = 0; v < 2 * BINS; ++v) acc[v] = 0.f;

    const int tid = threadIdx.x;
    for (int i = tid; i < nb; i += FTPB) {
        const float4* rec = (const float4*)(part + (size_t)i * (2 * BINS));
        float4 a = rec[0], b = rec[1], c = rec[2], d = rec[3], e = rec[4];
        acc[0]  += a.x; acc[1]  += a.y; acc[2]  += a.z; acc[3]  += a.w;
        acc[4]  += b.x; acc[5]  += b.y; acc[6]  += b.z; acc[7]  += b.w;
        acc[8]  += c.x; acc[9]  += c.y; acc[10] += c.z; acc[11] += c.w;
        acc[12] += d.x; acc[13] += d.y; acc[14] += d.z; acc[15] += d.w;
        acc[16] += e.x; acc[17] += e.y; acc[18] += e.z; acc[19] += e.w;
    }

#pragma unroll
    for (int v = 0; v < 2 * BINS; ++v) {
#pragma unroll
        for (int off = 1; off <= 32; off <<= 1)
            acc[v] += __shfl_xor(acc[v], off, 64);
    }

    __shared__ float sh[2 * BINS][16];
    const int wv = tid >> 6, lane = tid & 63;
    if (lane == 0) {
#pragma unroll
        for (int v = 0; v < 2 * BINS; ++v) sh[v][wv] = acc[v];
    }
    __syncthreads();
    if (tid < 2 * BINS) {
        float s = 0.f;
#pragma unroll
        for (int g = 0; g < 16; ++g) s += sh[tid][g];
        sh[tid][0] = s;
    }
    __syncthreads();

    if (tid == 0) {
        float ti = 0.f; int nbn = 0;
        float cnts[BINS];
#pragma unroll
        for (int b = 0; b < BINS; ++b) {
            cnts[b] = sh[BINS + b][0];
            ti += cnts[b];
            nbn += (cnts[b] > 0.f) ? 1 : 0;
        }
        float total = fmaxf(ti, 1.f);
        float nf    = (float)(nbn > 0 ? nbn : 1);
        float loss  = 0.f;
#pragma unroll
        for (int b = 0; b < BINS; ++b) {
            if (cnts[b] > 0.f) {
                float w = (total / cnts[b]) / nf;   // w_bin[b]
                loss += w * sh[b][0];
            }
        }
        out[0] = loss / total * 1.0f;  // LOSS_WEIGHT = 1.0
    }
}

extern "C" void kernel_launch(void* const* d_in, const int* in_sizes, int n_in,
                              void* d_out, int out_size, void* d_ws, size_t ws_size,
                              hipStream_t stream)
{
    const float4* pred4 = (const float4*)d_in[0];
    const int4*   tgt4  = (const int4*)d_in[1];
    const int4*   lw4   = (const int4*)d_in[2];

    const int n  = in_sizes[0];
    const int n4 = n / 4;

    int nb = (n4 + TPB - 1) / TPB;
    if (nb > NB_MAX) nb = NB_MAX;
    int ws_cap = (int)(ws_size / (2 * BINS * sizeof(float)));
    if (nb > ws_cap) nb = ws_cap;
    if (nb < 1) nb = 1;

    float* part = (float*)d_ws;   // [nb][2*BINS]

    ghmc_hist_kernel<<<nb, TPB, 0, stream>>>(pred4, tgt4, lw4, part, n4, n);
    ghmc_final_kernel<<<1, FTPB, 0, stream>>>(part, (float*)d_out, nb);
}

// Round 11
// 37.773 us; speedup vs baseline: 3.4096x; 3.4096x over previous
//
#include <hip/hip_runtime.h>

#define BINS 10
#define TPB  256
#define NB_MAX 2048
#define FTPB 1024   // finalize block size
#define KPACK 16384.0f
#define LN2f  0.69314718055994531f

// Pass 1: per-bin (count,sum) fused into ONE accumulator per bin:
//   acc[b] += (bin==b) ? (bce2 + 16384) : 0     (bce2 = softplus(q)/ln2)
// Per-thread S2_b < ~500 << 16384: C = floor(acc/16384), S2 = acc - 16384C.
// bce kept in LOG2 domain (v_log native output); final kernel scales by ln2.
// Native transcendentals FORCED via __builtin_amdgcn_{exp2f,logf,rcpf}
// (R6-R9 audit: dynamic instr mass ~3x source count; precise OCML exp/log
// expansions are the prime suspect).
// One-hot select: sel = sbfe(1<<bin, b, 1) in {0,-1}; acc[b] += sel & vbits.
// KPACK=16384 lets the FUSED acc go through the shfl tree directly (40 LDS
// ops/wave instead of 80); 16-lane leaders separate C/S2 afterwards.
__global__ __launch_bounds__(TPB, 4) void ghmc_hist_kernel(
    const float4* __restrict__ pred4,
    const int4*   __restrict__ tgt4,
    const int4*   __restrict__ lw4,
    float* __restrict__ part,      // [nb][2*BINS]
    int n4, int n)
{
    float acc[BINS];
#pragma unroll
    for (int b = 0; b < BINS; ++b) acc[b] = 0.f;

    auto proc = [&](float p, int t, int w) {
        // q = t ? -p : p  ==>  sigmoid(q) = g,  softplus(q) = bce
        float q     = __int_as_float(__float_as_int(p) ^ (t << 31));
        float e     = __builtin_amdgcn_exp2f(fabsf(q) * -1.44269504089f); // e^-|q|
        float d     = 1.f + e;
        float r     = __builtin_amdgcn_rcpf(d);
        float num   = (q >= 0.f) ? 1.0f : e;      // sigmoid numerator
        float sig10 = num * (10.f * r);           // 10*sigmoid(q) in [0,10]
        int bin     = (int)sig10;
        bin = bin < (BINS - 1) ? bin : (BINS - 1);
        // softplus(q) in log2 domain: log2(d) + max(q,0)*log2e
        float bce2  = fmaf(fmaxf(q, 0.f), 1.44269504089f,
                           __builtin_amdgcn_logf(d));
        int   vm    = 0 - (int)(w > 0);           // all-ones if valid
        float v     = bce2 + KPACK;
        int   vbits = __float_as_int(v) & vm;     // invalid -> +0.0 everywhere
        int   bit   = 1 << bin;
#pragma unroll
        for (int b = 0; b < BINS; ++b) {
            int sel = __builtin_amdgcn_sbfe(bit, b, 1);   // {0,-1}
            acc[b] += __int_as_float(sel & vbits);
        }
    };

    const int tid    = threadIdx.x;
    const int stride = gridDim.x * TPB;
    const int base   = blockIdx.x * TPB + tid;
    const int full   = n4 / stride;   // uniform trip count (5 at bench shape)

    int i = base;
    float4 pA; int4 tA, wA;
    if (full > 0) { pA = pred4[i]; tA = tgt4[i]; wA = lw4[i]; }
    for (int k = 0; k < full - 1; ++k) {
        const int j = i + stride;
        float4 pB = pred4[j]; int4 tB = tgt4[j]; int4 wB = lw4[j];
        proc(pA.x, tA.x, wA.x); proc(pA.y, tA.y, wA.y);
        proc(pA.z, tA.z, wA.z); proc(pA.w, tA.w, wA.w);
        pA = pB; tA = tB; wA = wB;
        i = j;
    }
    if (full > 0) {
        proc(pA.x, tA.x, wA.x); proc(pA.y, tA.y, wA.y);
        proc(pA.z, tA.z, wA.z); proc(pA.w, tA.w, wA.w);
    }
    // remainder quad (cold at bench shape)
    {
        const int j = base + full * stride;
        if (j < n4) {
            float4 p = pred4[j]; int4 t = tgt4[j]; int4 w = lw4[j];
            proc(p.x, t.x, w.x); proc(p.y, t.y, w.y);
            proc(p.z, t.z, w.z); proc(p.w, t.w, w.w);
        }
    }
    // scalar tail (cold at bench shape)
    if (blockIdx.x == 0 && tid < (n & 3)) {
        const float* predf = (const float*)pred4;
        const int*   tgtf  = (const int*)tgt4;
        const int*   lwf   = (const int*)lw4;
        const int j = n4 * 4 + tid;
        proc(predf[j], tgtf[j], lwf[j]);
    }

    // 4-level xor reduce within 16-lane groups on the FUSED accumulators.
    // Group total <= 16*20*16407 ~ 5.3M < 2^24: count part stays exact.
#pragma unroll
    for (int b = 0; b < BINS; ++b) {
#pragma unroll
        for (int off = 1; off <= 8; off <<= 1)
            acc[b] += __shfl_xor(acc[b], off, 64);
    }

    // 16 group leaders separate C/S2, then 20 threads write the block record
    __shared__ float red[2 * BINS][16];   // 1.28 KB
    const int grp = tid >> 4;
    if ((tid & 15) == 0) {
#pragma unroll
        for (int b = 0; b < BINS; ++b) {
            float Cf = floorf(acc[b] * (1.f / KPACK));
            red[b][grp]        = acc[b] - KPACK * Cf;   // S2 (log2 scale)
            red[BINS + b][grp] = Cf;                    // count
        }
    }
    __syncthreads();
    if (tid < 2 * BINS) {
        float v = 0.f;
#pragma unroll
        for (int g = 0; g < 16; ++g) v += red[tid][g];
        part[blockIdx.x * (2 * BINS) + tid] = v;   // contiguous record
    }
}

// Pass 2: reduce nb 20-float records with full ILP, compute the scalar loss.
// Sums arrive in log2 scale -> multiply by ln2 here.
__global__ __launch_bounds__(FTPB) void ghmc_final_kernel(
    const float* __restrict__ part, float* __restrict__ out, int nb)
{
    float acc[2 * BINS];
#pragma unroll
    for (int v = 0; v < 2 * BINS; ++v) acc[v] = 0.f;

    const int tid = threadIdx.x;
    for (int i = tid; i < nb; i += FTPB) {
        const float4* rec = (const float4*)(part + (size_t)i * (2 * BINS));
        float4 a = rec[0], b = rec[1], c = rec[2], d = rec[3], e = rec[4];
        acc[0]  += a.x; acc[1]  += a.y; acc[2]  += a.z; acc[3]  += a.w;
        acc[4]  += b.x; acc[5]  += b.y; acc[6]  += b.z; acc[7]  += b.w;
        acc[8]  += c.x; acc[9]  += c.y; acc[10] += c.z; acc[11] += c.w;
        acc[12] += d.x; acc[13] += d.y; acc[14] += d.z; acc[15] += d.w;
        acc[16] += e.x; acc[17] += e.y; acc[18] += e.z; acc[19] += e.w;
    }

#pragma unroll
    for (int v = 0; v < 2 * BINS; ++v) {
#pragma unroll
        for (int off = 1; off <= 32; off <<= 1)
            acc[v] += __shfl_xor(acc[v], off, 64);
    }

    __shared__ float sh[2 * BINS][16];
    const int wv = tid >> 6, lane = tid & 63;
    if (lane == 0) {
#pragma unroll
        for (int v = 0; v < 2 * BINS; ++v) sh[v][wv] = acc[v];
    }
    __syncthreads();
    if (tid < 2 * BINS) {
        float s = 0.f;
#pragma unroll
        for (int g = 0; g < 16; ++g) s += sh[tid][g];
        sh[tid][0] = s;
    }
    __syncthreads();

    if (tid == 0) {
        float ti = 0.f; int nbn = 0;
        float cnts[BINS];
#pragma unroll
        for (int b = 0; b < BINS; ++b) {
            cnts[b] = sh[BINS + b][0];
            ti += cnts[b];
            nbn += (cnts[b] > 0.f) ? 1 : 0;
        }
        float total = fmaxf(ti, 1.f);
        float nf    = (float)(nbn > 0 ? nbn : 1);
        float loss  = 0.f;
#pragma unroll
        for (int b = 0; b < BINS; ++b) {
            if (cnts[b] > 0.f) {
                float w = (total / cnts[b]) / nf;       // w_bin[b]
                loss += w * (sh[b][0] * LN2f);          // S = S2 * ln2
            }
        }
        out[0] = loss / total * 1.0f;  // LOSS_WEIGHT = 1.0
    }
}

extern "C" void kernel_launch(void* const* d_in, const int* in_sizes, int n_in,
                              void* d_out, int out_size, void* d_ws, size_t ws_size,
                              hipStream_t stream)
{
    const float4* pred4 = (const float4*)d_in[0];
    const int4*   tgt4  = (const int4*)d_in[1];
    const int4*   lw4   = (const int4*)d_in[2];

    const int n  = in_sizes[0];
    const int n4 = n / 4;

    int nb = (n4 + TPB - 1) / TPB;
    if (nb > NB_MAX) nb = NB_MAX;
    int ws_cap = (int)(ws_size / (2 * BINS * sizeof(float)));
    if (nb > ws_cap) nb = ws_cap;
    if (nb < 1) nb = 1;

    float* part = (float*)d_ws;   // [nb][2*BINS]

    ghmc_hist_kernel<<<nb, TPB, 0, stream>>>(pred4, tgt4, lw4, part, n4, n);
    ghmc_final_kernel<<<1, FTPB, 0, stream>>>(part, (float*)d_out, nb);
}

// Round 12
// 36.004 us; speedup vs baseline: 3.5771x; 1.0491x over previous
//
#include <hip/hip_runtime.h>

#define BINS 10
#define TPB  256
#define NB_MAX 2048
#define FTPB 1024   // finalize block size
#define KPACK 16384.0f
#define LN2f   0.69314718055994531f
#define LOG2Ef 1.44269504088896f

// Fire-and-forget global->LDS load, 16 bytes, per-thread slot.
// Dest must be wave-uniform base + lane*16: lds[buf][tid] is tid-linear. OK.
template <typename T>
__device__ __forceinline__ void gload16(const T* g, T* l) {
    __builtin_amdgcn_global_load_lds(
        (const __attribute__((address_space(1))) void*)g,
        (__attribute__((address_space(3))) void*)l, 16, 0, 0);
}

// Pass 1. Structure (round 12):
//  - LDS prefetch queue, distance 2, NO barriers: each thread stages its own
//    pred/tgt/lw quad into private LDS slots via global_load_lds (compiler
//    cannot sink these into uses -- R7/R9/R11 showed it sinks register
//    loads, fully exposing ~2000cy/iter of latency; VGPR=28 proved it).
//  - asm s_waitcnt vmcnt(3): wait ONLY the oldest staged tile; the newer
//    tile's 3 loads stay in flight under the proc window (T4, counted).
//  - lgkmcnt(0) fence after ds_reads before re-staging same buffer (race).
//  - threshold-prefix binning: bin = sum_k (q >= logit(k/10)); no sigmoid,
//    no rcp. A[k] += (q>=Q[k]) ? v : 0 with v = bce2+KPACK fused (count in
//    floor(v/KPACK)); prefix un-diffed in the finalize kernel.
__global__ __launch_bounds__(TPB, 4) void ghmc_hist_kernel(
    const float4* __restrict__ pred4,
    const int4*   __restrict__ tgt4,
    const int4*   __restrict__ lw4,
    float* __restrict__ part,      // [nb][2*BINS]
    int n4, int n)
{
    __shared__ float4 Lp[2][TPB];
    __shared__ int4   Lt[2][TPB];
    __shared__ int4   Lw[2][TPB];
    __shared__ float  red[2 * BINS][16];

    float A[BINS];
#pragma unroll
    for (int b = 0; b < BINS; ++b) A[b] = 0.f;

    const float Q[9] = {-2.19722458f, -1.38629436f, -0.84729786f,
                        -0.40546511f,  0.0f,         0.40546511f,
                         0.84729786f,  1.38629436f,  2.19722458f};

    auto proc = [&](float p, int t, int w) {
        // q = t ? -p : p;  g = sigmoid(q);  bce = softplus(q)
        float q    = __int_as_float(__float_as_int(p) ^ (int)((unsigned)t << 31));
        float e    = __builtin_amdgcn_exp2f(fabsf(q) * -LOG2Ef);   // e^-|q|
        float d    = 1.f + e;
        float bce2 = fmaf(fmaxf(q, 0.f), LOG2Ef,
                          __builtin_amdgcn_logf(d));               // softplus/ln2
        float v    = (w > 0) ? (bce2 + KPACK) : 0.f;
        A[0] += v;
#pragma unroll
        for (int k = 0; k < 9; ++k)
            A[k + 1] += (q >= Q[k]) ? v : 0.f;   // bin >= k+1  <=>  q >= Q[k]
    };

    const int tid    = threadIdx.x;
    const int stride = gridDim.x * TPB;
    const int base   = blockIdx.x * TPB + tid;
    const int full   = n4 / stride;   // uniform trip count (5 at bench shape)

    if (full >= 2) {
        // prologue: stage tiles 0 and 1 (6 loads in flight)
        gload16(&pred4[base],          &Lp[0][tid]);
        gload16(&tgt4 [base],          &Lt[0][tid]);
        gload16(&lw4  [base],          &Lw[0][tid]);
        gload16(&pred4[base + stride], &Lp[1][tid]);
        gload16(&tgt4 [base + stride], &Lt[1][tid]);
        gload16(&lw4  [base + stride], &Lw[1][tid]);

        for (int k = 0; k < full - 1; ++k) {
            asm volatile("s_waitcnt vmcnt(3)" ::: "memory");   // oldest tile done
            __builtin_amdgcn_sched_barrier(0);
            const int b2 = k & 1;
            float4 p = Lp[b2][tid];
            int4   t = Lt[b2][tid];
            int4   w = Lw[b2][tid];
            asm volatile("s_waitcnt lgkmcnt(0)" ::: "memory");  // reads retired
            __builtin_amdgcn_sched_barrier(0);
            if (k + 2 < full) {                 // re-stage freed buffer
                const int j = base + (k + 2) * stride;
                gload16(&pred4[j], &Lp[b2][tid]);
                gload16(&tgt4 [j], &Lt[b2][tid]);
                gload16(&lw4  [j], &Lw[b2][tid]);
            }
            proc(p.x, t.x, w.x); proc(p.y, t.y, w.y);
            proc(p.z, t.z, w.z); proc(p.w, t.w, w.w);
        }
        {   // last tile: everything must be drained
            asm volatile("s_waitcnt vmcnt(0)" ::: "memory");
            __builtin_amdgcn_sched_barrier(0);
            const int b2 = (full - 1) & 1;
            float4 p = Lp[b2][tid];
            int4   t = Lt[b2][tid];
            int4   w = Lw[b2][tid];
            proc(p.x, t.x, w.x); proc(p.y, t.y, w.y);
            proc(p.z, t.z, w.z); proc(p.w, t.w, w.w);
        }
    } else {
        for (int k = 0; k < full; ++k) {
            const int j = base + k * stride;
            float4 p = pred4[j]; int4 t = tgt4[j]; int4 w = lw4[j];
            proc(p.x, t.x, w.x); proc(p.y, t.y, w.y);
            proc(p.z, t.z, w.z); proc(p.w, t.w, w.w);
        }
    }
    // remainder quad (cold at bench shape)
    {
        const int j = base + full * stride;
        if (j < n4) {
            float4 p = pred4[j]; int4 t = tgt4[j]; int4 w = lw4[j];
            proc(p.x, t.x, w.x); proc(p.y, t.y, w.y);
            proc(p.z, t.z, w.z); proc(p.w, t.w, w.w);
        }
    }
    // scalar tail (cold at bench shape)
    if (blockIdx.x == 0 && tid < (n & 3)) {
        const float* predf = (const float*)pred4;
        const int*   tgtf  = (const int*)tgt4;
        const int*   lwf   = (const int*)lw4;
        const int j = n4 * 4 + tid;
        proc(predf[j], tgtf[j], lwf[j]);
    }

    // 4-level xor reduce of the 10 fused prefix accumulators (group<=5.3M<2^24)
#pragma unroll
    for (int b = 0; b < BINS; ++b) {
#pragma unroll
        for (int off = 1; off <= 8; off <<= 1)
            A[b] += __shfl_xor(A[b], off, 64);
    }

    // 16 group leaders separate prefix count / prefix sum; 20 threads write
    const int grp = tid >> 4;
    if ((tid & 15) == 0) {
#pragma unroll
        for (int b = 0; b < BINS; ++b) {
            float Cf = floorf(A[b] * (1.f / KPACK));
            red[b][grp]        = A[b] - KPACK * Cf;   // prefix S2 (log2 scale)
            red[BINS + b][grp] = Cf;                  // prefix count
        }
    }
    __syncthreads();
    if (tid < 2 * BINS) {
        float v = 0.f;
#pragma unroll
        for (int g = 0; g < 16; ++g) v += red[tid][g];
        part[blockIdx.x * (2 * BINS) + tid] = v;   // contiguous record
    }
}

// Pass 2: reduce nb 20-float records (rows 0..9 prefix-S2, 10..19 prefix-C),
// un-diff the prefixes, compute the scalar loss (S = S2 * ln2).
__global__ __launch_bounds__(FTPB) void ghmc_final_kernel(
    const float* __restrict__ part, float* __restrict__ out, int nb)
{
    float acc[2 * BINS];
#pragma unroll
    for (int v = 0; v < 2 * BINS; ++v) acc[v] = 0.f;

    const int tid = threadIdx.x;
    for (int i = tid; i < nb; i += FTPB) {
        const float4* rec = (const float4*)(part + (size_t)i * (2 * BINS));
        float4 a = rec[0], b = rec[1], c = rec[2], d = rec[3], e = rec[4];
        acc[0]  += a.x; acc[1]  += a.y; acc[2]  += a.z; acc[3]  += a.w;
        acc[4]  += b.x; acc[5]  += b.y; acc[6]  += b.z; acc[7]  += b.w;
        acc[8]  += c.x; acc[9]  += c.y; acc[10] += c.z; acc[11] += c.w;
        acc[12] += d.x; acc[13] += d.y; acc[14] += d.z; acc[15] += d.w;
        acc[16] += e.x; acc[17] += e.y; acc[18] += e.z; acc[19] += e.w;
    }

#pragma unroll
    for (int v = 0; v < 2 * BINS; ++v) {
#pragma unroll
        for (int off = 1; off <= 32; off <<= 1)
            acc[v] += __shfl_xor(acc[v], off, 64);
    }

    __shared__ float sh[2 * BINS][16];
    const int wv = tid >> 6, lane = tid & 63;
    if (lane == 0) {
#pragma unroll
        for (int v = 0; v < 2 * BINS; ++v) sh[v][wv] = acc[v];
    }
    __syncthreads();
    if (tid < 2 * BINS) {
        float s = 0.f;
#pragma unroll
        for (int g = 0; g < 16; ++g) s += sh[tid][g];
        sh[tid][0] = s;
    }
    __syncthreads();

    if (tid == 0) {
        float PS2[BINS + 1], PC[BINS + 1];
        PS2[BINS] = 0.f; PC[BINS] = 0.f;
#pragma unroll
        for (int b = 0; b < BINS; ++b) { PS2[b] = sh[b][0]; PC[b] = sh[BINS + b][0]; }

        float ti = PC[0];          // total valid = prefix count at level 0
        int nbn = 0;
        float cnts[BINS], sums[BINS];
#pragma unroll
        for (int b = 0; b < BINS; ++b) {
            cnts[b] = PC[b]  - PC[b + 1];    // exact integer diff
            sums[b] = PS2[b] - PS2[b + 1];
            nbn += (cnts[b] > 0.5f) ? 1 : 0;
        }
        float total = fmaxf(ti, 1.f);
        float nf    = (float)(nbn > 0 ? nbn : 1);
        float loss  = 0.f;
#pragma unroll
        for (int b = 0; b < BINS; ++b) {
            if (cnts[b] > 0.5f) {
                float w = (total / cnts[b]) / nf;     // w_bin[b]
                loss += w * (sums[b] * LN2f);         // S = S2 * ln2
            }
        }
        out[0] = loss / total * 1.0f;  // LOSS_WEIGHT = 1.0
    }
}

extern "C" void kernel_launch(void* const* d_in, const int* in_sizes, int n_in,
                              void* d_out, int out_size, void* d_ws, size_t ws_size,
                              hipStream_t stream)
{
    const float4* pred4 = (const float4*)d_in[0];
    const int4*   tgt4  = (const int4*)d_in[1];
    const int4*   lw4   = (const int4*)d_in[2];

    const int n  = in_sizes[0];
    const int n4 = n / 4;

    int nb = (n4 + TPB - 1) / TPB;
    if (nb > NB_MAX) nb = NB_MAX;
    int ws_cap = (int)(ws_size / (2 * BINS * sizeof(float)));
    if (nb > ws_cap) nb = ws_cap;
    if (nb < 1) nb = 1;

    float* part = (float*)d_ws;   // [nb][2*BINS]

    ghmc_hist_kernel<<<nb, TPB, 0, stream>>>(pred4, tgt4, lw4, part, n4, n);
    ghmc_final_kernel<<<1, FTPB, 0, stream>>>(part, (float*)d_out, nb);
}